// Round 8
// baseline (1709.981 us; speedup 1.0000x reference)
//
#include <hip/hip_runtime.h>
#include <math.h>

#define T_ 128
#define B_ 32
#define V_ 33278
#define E_ 400

typedef __bf16 bf16x8 __attribute__((ext_vector_type(8)));
typedef float f32x4 __attribute__((ext_vector_type(4)));

#define AGENT_LD(p) __hip_atomic_load((p), __ATOMIC_RELAXED, __HIP_MEMORY_SCOPE_AGENT)
#define AGENT_ST(p, v) __hip_atomic_store((p), (v), __ATOMIC_RELAXED, __HIP_MEMORY_SCOPE_AGENT)

__device__ __forceinline__ float exp2f_(float x) {
  float r;
  asm("v_exp_f32 %0, %1" : "=v"(r) : "v"(x));
  return r;
}
__device__ __forceinline__ float rcpf_(float x) {
  float r;
  asm("v_rcp_f32 %0, %1" : "=v"(r) : "v"(x));
  return r;
}
__device__ __forceinline__ float sigf_(float x) { return rcpf_(1.0f + exp2f_(-1.44269504f * x)); }
__device__ __forceinline__ float tanhf_(float x) {
  float t = exp2f_(2.88539008f * x);
  return 1.0f - 2.0f * rcpf_(t + 1.0f);
}

__device__ __forceinline__ unsigned short f2bf(float f) {
  unsigned u = __float_as_uint(f);
  unsigned lsb = (u >> 16) & 1;
  return (unsigned short)((u + 0x7FFFu + lsb) >> 16);
}

__device__ __forceinline__ void gload16(const unsigned short* g, unsigned short* l) {
  __builtin_amdgcn_global_load_lds((const __attribute__((address_space(1))) void*)g,
                                   (__attribute__((address_space(3))) void*)l, 16, 0, 0);
}

// ---------------- embedding gather -> bf16 padded [T*B][416] ----------------
__global__ void embed_kernel(const int* __restrict__ idx, const float* __restrict__ W,
                             unsigned short* __restrict__ x) {
  int i = blockIdx.x * blockDim.x + threadIdx.x;
  if (i >= T_ * B_ * 416) return;
  int k = i % 416;
  int tb = i / 416;
  x[i] = (k < E_) ? f2bf(W[(size_t)idx[tb] * E_ + k]) : 0;
}

// ---------------- merged fp32 -> bf16 weight conversion (7 jobs, 1 launch) ----------------
struct CJob {
  const float* in;
  unsigned short* out;
  int N, K, Kp;
  long base;  // start offset in the flat virtual index space
};
struct CJobs {
  CJob j[7];
  long total;
};
__global__ void convAll(CJobs J) {
  long stride = (long)gridDim.x * blockDim.x;
  for (long i = (long)blockIdx.x * blockDim.x + threadIdx.x; i < J.total; i += stride) {
    int jj = 0;
#pragma unroll
    for (int q = 1; q < 7; ++q)
      if (i >= J.j[q].base) jj = q;
    const CJob& c = J.j[jj];
    long local = i - c.base;
    int k = (int)(local % c.Kp);
    long n = local / c.Kp;
    c.out[local] = (n < c.N && k < c.K) ? f2bf(c.in[n * (long)c.K + k]) : 0;
  }
}

// ---------------- bf16 MFMA GEMM: C[M,N] = A[M,Kp] * B[N,Kp]^T + bias ----------------
// swz=1: flat grid, bijective n-chunked XCD swizzle (n-tile panels L2-resident per XCD).
// Epilogue remap (gateN>0): n (gate-major g*gateN+u) -> col = u*4 + g  (unit-major xg)
__global__ __launch_bounds__(256) void gemm_bf16(const unsigned short* __restrict__ A,
                                                 const unsigned short* __restrict__ B,
                                                 const float* __restrict__ bias0,
                                                 const float* __restrict__ bias1,
                                                 float* __restrict__ C, int M, int Kp, int ldc,
                                                 int realN, int gateN, int swz) {
  int bx, by;
  if (swz) {
    int bid = blockIdx.x;
    int xcd = bid & 7, loc = bid >> 3;
    int nt = xcd * 33 + (loc >> 5);
    if (nt >= 260) return;  // phantom tile (uniform per block, before any barrier)
    bx = nt;
    by = loc & 31;
  } else {
    bx = blockIdx.x;
    by = blockIdx.y;
  }
  __shared__ __align__(16) unsigned short lsA[4 * 128 * 8];
  __shared__ __align__(16) unsigned short lsB[4 * 128 * 8];
  const int tid = threadIdx.x;
  const int lane = tid & 63;
  const int w = tid >> 6;
  const int wm = (w >> 1) * 64;
  const int wn = (w & 1) * 64;
  const int lr = lane & 15;
  const int kq = lane >> 4;
  const int m0 = by * 128;
  const int n0 = bx * 128;

  f32x4 acc[4][4] = {};

  const int kiters = Kp >> 5;
  for (int kt = 0; kt < kiters; ++kt) {
    const int k0 = kt << 5;
#pragma unroll
    for (int q = 0; q < 2; ++q) {
      int s = w + q * 4;
      int kc = s >> 1, rb = (s & 1) * 64;
      gload16(A + (size_t)(m0 + rb + lane) * Kp + k0 + kc * 8, lsA + s * 512);
      gload16(B + (size_t)(n0 + rb + lane) * Kp + k0 + kc * 8, lsB + s * 512);
    }
    __syncthreads();

    bf16x8 af[4], bf[4];
#pragma unroll
    for (int mf = 0; mf < 4; ++mf)
      af[mf] = *(const bf16x8*)&lsA[(kq * 128 + wm + mf * 16 + lr) * 8];
#pragma unroll
    for (int nf = 0; nf < 4; ++nf)
      bf[nf] = *(const bf16x8*)&lsB[(kq * 128 + wn + nf * 16 + lr) * 8];
#pragma unroll
    for (int mf = 0; mf < 4; ++mf)
#pragma unroll
      for (int nf = 0; nf < 4; ++nf)
        acc[mf][nf] = __builtin_amdgcn_mfma_f32_16x16x32_bf16(af[mf], bf[nf], acc[mf][nf], 0, 0, 0);
    __syncthreads();
  }

#pragma unroll
  for (int nf = 0; nf < 4; ++nf) {
    int n = n0 + wn + nf * 16 + lr;
    if (n >= realN) continue;
    float bsum = 0.0f;
    if (bias0) bsum += bias0[n];
    if (bias1) bsum += bias1[n];
    int col = n;
    if (gateN > 0) {
      int g = (n >= gateN) + (n >= 2 * gateN) + (n >= 3 * gateN);
      int u = n - g * gateN;
      col = u * 4 + g;
    }
#pragma unroll
    for (int mf = 0; mf < 4; ++mf) {
      int mbase = m0 + wm + mf * 16 + kq * 4;
#pragma unroll
      for (int r = 0; r < 4; ++r) C[(size_t)(mbase + r) * ldc + col] = acc[mf][nf][r] + bsum;
    }
  }
}

// ================= fused pipelined 3-layer LSTM recurrence =================
// Roles by blockIdx.x: [0,72) L0 rec | [72,144) L1 input-helper | [144,216) L1 rec
// | [216,242) L2 combined. 242 blocks x 512 thr, 1 block/CU.
// h-chains are WRITE-ONCE per launch: published via agent u64 stores (MALL),
// staged by consumers AFTER flag via NORMAL uint4 loads (L2-shared; dispatch-start
// acquire invalidates L2, validated by r7's cross-dispatch decoder reads).
// Ring slots are REUSED every 16 steps -> ring reads/writes must stay agent-scope.

struct FP {
  const float* xg0;   // [4096][4608] fp32 (unit-major gates), L0 C-init
  float* ring;        // [16][32][4608] fp32, helper -> L1 rec (agent-only access)
  const unsigned short *whh0, *wih1, *whh1, *wih2, *whh2;
  const float *h0_0, *c0_0, *h0_1, *c0_1, *h0_2, *c0_2;
  const float *bih1, *bhh1, *bih2, *bhh2;
  unsigned short *xc1, *xc2, *xc3;  // chains: [(1+T)*32][KP]
  float *oh0, *oc0, *oh1, *oc1, *oh2, *oc2;
  int* flags;
};

__device__ __forceinline__ void pollset(const int* f, int hf, int n, int tgt) {
  int lane = threadIdx.x & 63;
  for (;;) {
    int v = (lane < n) ? AGENT_LD(&f[((lane << 1) + hf) * 16]) : tgt;
    if (__all(v >= tgt)) break;
  }
}

// normal-load staging (L2 path): slab rows are 16B-aligned, write-once
template <int KT>
__device__ __forceinline__ void stage(const unsigned short* slab, unsigned short* lds) {
  constexpr int KP = KT * 32, KPP = KP + 8, C16 = KP / 8, NCH = 16 * C16;
  constexpr int NIT = (NCH + 511) / 512;
  const int tid = threadIdx.x;
  uint4 d[NIT];
#pragma unroll
  for (int i = 0; i < NIT; ++i) {
    int c = tid + i * 512;
    if (c < NCH) d[i] = *(const uint4*)(slab + (size_t)(c / C16) * KP + (c % C16) * 8);
  }
#pragma unroll
  for (int i = 0; i < NIT; ++i) {
    int c = tid + i * 512;
    if (c < NCH) *(uint4*)&lds[(c / C16) * KPP + (c % C16) * 8] = d[i];
  }
}

// combined two-slab stage: issue ALL loads before committing either (overlap roundtrips)
template <int KTA, int KTB>
__device__ __forceinline__ void stage2(const unsigned short* slabA, const unsigned short* slabB,
                                       unsigned short* ldsA, unsigned short* ldsB) {
  constexpr int KPA = KTA * 32, KPPA = KPA + 8, CA = KPA / 8, NA = 16 * CA;
  constexpr int NITA = (NA + 511) / 512;
  constexpr int KPB = KTB * 32, KPPB = KPB + 8, CB = KPB / 8, NB = 16 * CB;
  constexpr int NITB = (NB + 511) / 512;
  const int tid = threadIdx.x;
  uint4 dA[NITA], dB[NITB];
#pragma unroll
  for (int i = 0; i < NITA; ++i) {
    int c = tid + i * 512;
    if (c < NA) dA[i] = *(const uint4*)(slabA + (size_t)(c / CA) * KPA + (c % CA) * 8);
  }
#pragma unroll
  for (int i = 0; i < NITB; ++i) {
    int c = tid + i * 512;
    if (c < NB) dB[i] = *(const uint4*)(slabB + (size_t)(c / CB) * KPB + (c % CB) * 8);
  }
#pragma unroll
  for (int i = 0; i < NITA; ++i) {
    int c = tid + i * 512;
    if (c < NA) *(uint4*)&ldsA[(c / CA) * KPPA + (c % CA) * 8] = dA[i];
  }
#pragma unroll
  for (int i = 0; i < NITB; ++i) {
    int c = tid + i * 512;
    if (c < NB) *(uint4*)&ldsB[(c / CB) * KPPB + (c % CB) * 8] = dB[i];
  }
}

template <int KT>
__device__ __forceinline__ void load_aw(const unsigned short* w, int dh, int U0, int wv, int lm,
                                        int kq, bf16x8* aw) {
  const int ga = lm & 3, ula = lm >> 2;
  const int ua = U0 + wv * 4 + ula;
  const unsigned short* wr = w + (size_t)(ga * dh + (ua < dh ? ua : 0)) * (KT * 32);
#pragma unroll
  for (int kt = 0; kt < KT; ++kt) aw[kt] = *(const bf16x8*)&wr[kt * 32 + kq * 8];
}

template <int KT>
__device__ __forceinline__ void mm4(const bf16x8* aw, const unsigned short* lds, int lm, int kq,
                                    f32x4& a0, f32x4& a1, f32x4& a2, f32x4& a3) {
  constexpr int KPP = KT * 32 + 8;
  const unsigned short* rp = lds + lm * KPP + kq * 8;
#pragma unroll
  for (int kt = 0; kt < KT; kt += 4) {
    a0 = __builtin_amdgcn_mfma_f32_16x16x32_bf16(aw[kt], *(const bf16x8*)&rp[kt * 32], a0, 0, 0, 0);
    if (kt + 1 < KT)
      a1 = __builtin_amdgcn_mfma_f32_16x16x32_bf16(aw[kt + 1], *(const bf16x8*)&rp[(kt + 1) * 32],
                                                   a1, 0, 0, 0);
    if (kt + 2 < KT)
      a2 = __builtin_amdgcn_mfma_f32_16x16x32_bf16(aw[kt + 2], *(const bf16x8*)&rp[(kt + 2) * 32],
                                                   a2, 0, 0, 0);
    if (kt + 3 < KT)
      a3 = __builtin_amdgcn_mfma_f32_16x16x32_bf16(aw[kt + 3], *(const bf16x8*)&rp[(kt + 3) * 32],
                                                   a3, 0, 0, 0);
  }
}

__device__ __forceinline__ void pub_h(unsigned short* dst, float hn, bool vu, int kq) {
  unsigned hv = vu ? (unsigned)f2bf(hn) : 0u;
  unsigned t16 = (unsigned)__shfl_xor((int)hv, 16);
  unsigned v32 = (kq & 1) ? (t16 | (hv << 16)) : (hv | (t16 << 16));
  unsigned o32 = (unsigned)__shfl_xor((int)v32, 32);
  if (kq == 0)
    AGENT_ST((unsigned long long*)dst, (unsigned long long)v32 | ((unsigned long long)o32 << 32));
}

__global__ __launch_bounds__(512, 2) void fused_lstm(FP P) {
  __shared__ __align__(16) unsigned short sbuf[16 * 1160 + 16 * 424];
  const int tid = threadIdx.x;
  const int lane = tid & 63;
  const int wv = tid >> 6;
  const int lm = lane & 15;
  const int kq = lane >> 4;
  const int bid = blockIdx.x;
  int* f0 = P.flags;
  int* fh = P.flags + 72 * 16;
  int* f1 = P.flags + 144 * 16;
  int* f2 = P.flags + 216 * 16;

  if (bid < 72) {  // ---------------- L0 recurrence ----------------
    constexpr int KT = 36, KP = 1152;
    const int hf = bid & 1, gid = bid >> 1, U0 = gid * 32;
    const int gb = hf * 16 + lm, un = U0 + wv * 4 + kq;
    const bool vu = un < 1150;
    bf16x8 aw[KT];
    load_aw<KT>(P.whh0, 1150, U0, wv, lm, kq, aw);
    float creg = vu ? P.c0_0[gb * 1150 + un] : 0.f;
    pub_h(P.xc1 + (size_t)gb * KP + U0 + wv * 4, vu ? P.h0_0[gb * 1150 + un] : 0.f, vu, kq);
    asm volatile("s_waitcnt vmcnt(0)" ::: "memory");
    __syncthreads();
    if (tid == 0) AGENT_ST(&f0[(gid * 2 + hf) * 16], 1);
    for (int t = 0; t < T_; ++t) {
      f32x4 cinit = *(const f32x4*)&P.xg0[(size_t)(t * 32 + gb) * 4608 + un * 4];
      if (wv == 0) pollset(f0, hf, 36, t + 1);
      else if (wv == 1 && t >= 8) pollset(f1, hf, 36, t - 7);  // ring backpressure
      __syncthreads();
      stage<KT>(P.xc1 + (size_t)(t * 32 + hf * 16) * KP, sbuf);
      __syncthreads();
      f32x4 a0 = cinit, a1 = {0.f, 0.f, 0.f, 0.f}, a2 = {0.f, 0.f, 0.f, 0.f},
            a3 = {0.f, 0.f, 0.f, 0.f};
      mm4<KT>(aw, sbuf, lm, kq, a0, a1, a2, a3);
      float gi = a0[0] + a1[0] + a2[0] + a3[0], gf = a0[1] + a1[1] + a2[1] + a3[1];
      float gg = a0[2] + a1[2] + a2[2] + a3[2], go = a0[3] + a1[3] + a2[3] + a3[3];
      float cn = sigf_(gf) * creg + sigf_(gi) * tanhf_(gg);
      float hn = sigf_(go) * tanhf_(cn);
      creg = cn;
      pub_h(P.xc1 + (size_t)((t + 1) * 32 + gb) * KP + U0 + wv * 4, hn, vu, kq);
      if (t == T_ - 1 && vu) { P.oh0[gb * 1150 + un] = hn; P.oc0[gb * 1150 + un] = cn; }
      asm volatile("s_waitcnt vmcnt(0)" ::: "memory");
      __syncthreads();
      if (tid == 0) AGENT_ST(&f0[(gid * 2 + hf) * 16], t + 2);
    }
  } else if (bid < 144) {  // ---------------- L1 input-projection helper ----------------
    constexpr int KT = 36, KP = 1152;
    const int idx = bid - 72, hf = idx & 1, gid = idx >> 1, U0 = gid * 32;
    const int gb = hf * 16 + lm, un = U0 + wv * 4 + kq;
    const bool vu = un < 1150;
    bf16x8 aw[KT];
    load_aw<KT>(P.wih1, 1150, U0, wv, lm, kq, aw);
    f32x4 bini = {0.f, 0.f, 0.f, 0.f};
    if (vu) {
#pragma unroll
      for (int g = 0; g < 4; ++g) bini[g] = P.bih1[g * 1150 + un] + P.bhh1[g * 1150 + un];
    }
    for (int t = 0; t < T_; ++t) {
      if (wv == 0) pollset(f0, hf, 36, t + 2);  // h0 output of step t = chain0 row t+1
      __syncthreads();
      stage<KT>(P.xc1 + (size_t)((t + 1) * 32 + hf * 16) * KP, sbuf);
      __syncthreads();
      f32x4 a0 = bini, a1 = {0.f, 0.f, 0.f, 0.f}, a2 = {0.f, 0.f, 0.f, 0.f},
            a3 = {0.f, 0.f, 0.f, 0.f};
      mm4<KT>(aw, sbuf, lm, kq, a0, a1, a2, a3);
      float r0 = a0[0] + a1[0] + a2[0] + a3[0], r1 = a0[1] + a1[1] + a2[1] + a3[1];
      float r2 = a0[2] + a1[2] + a2[2] + a3[2], r3 = a0[3] + a1[3] + a2[3] + a3[3];
      unsigned long long* dst =
          (unsigned long long*)(P.ring + ((size_t)(t & 15) * 32 + gb) * 4608 + un * 4);
      AGENT_ST(dst, ((unsigned long long)__float_as_uint(r1) << 32) | __float_as_uint(r0));
      AGENT_ST(dst + 1, ((unsigned long long)__float_as_uint(r3) << 32) | __float_as_uint(r2));
      asm volatile("s_waitcnt vmcnt(0)" ::: "memory");
      __syncthreads();
      if (tid == 0) AGENT_ST(&fh[(gid * 2 + hf) * 16], t + 1);
    }
  } else if (bid < 216) {  // ---------------- L1 recurrence ----------------
    constexpr int KT = 36, KP = 1152;
    const int idx = bid - 144, hf = idx & 1, gid = idx >> 1, U0 = gid * 32;
    const int gb = hf * 16 + lm, un = U0 + wv * 4 + kq;
    const bool vu = un < 1150;
    bf16x8 aw[KT];
    load_aw<KT>(P.whh1, 1150, U0, wv, lm, kq, aw);
    float creg = vu ? P.c0_1[gb * 1150 + un] : 0.f;
    pub_h(P.xc2 + (size_t)gb * KP + U0 + wv * 4, vu ? P.h0_1[gb * 1150 + un] : 0.f, vu, kq);
    asm volatile("s_waitcnt vmcnt(0)" ::: "memory");
    __syncthreads();
    if (tid == 0) AGENT_ST(&f1[(gid * 2 + hf) * 16], 1);
    for (int t = 0; t < T_; ++t) {
      if (wv == 0) pollset(f1, hf, 36, t + 1);
      else if (wv == 1) {
        for (;;) {
          int v = AGENT_LD(&fh[(gid * 2 + hf) * 16]);
          if (__all(v >= t + 1)) break;
        }
      }
      __syncthreads();
      stage<KT>(P.xc2 + (size_t)(t * 32 + hf * 16) * KP, sbuf);
      const unsigned long long* rp =
          (const unsigned long long*)(P.ring + ((size_t)(t & 15) * 32 + gb) * 4608 + un * 4);
      unsigned long long q0 = AGENT_LD(rp), q1 = AGENT_LD(rp + 1);
      __syncthreads();
      f32x4 a0, a1 = {0.f, 0.f, 0.f, 0.f}, a2 = {0.f, 0.f, 0.f, 0.f}, a3 = {0.f, 0.f, 0.f, 0.f};
      a0[0] = __uint_as_float((unsigned)q0);
      a0[1] = __uint_as_float((unsigned)(q0 >> 32));
      a0[2] = __uint_as_float((unsigned)q1);
      a0[3] = __uint_as_float((unsigned)(q1 >> 32));
      mm4<KT>(aw, sbuf, lm, kq, a0, a1, a2, a3);
      float gi = a0[0] + a1[0] + a2[0] + a3[0], gf = a0[1] + a1[1] + a2[1] + a3[1];
      float gg = a0[2] + a1[2] + a2[2] + a3[2], go = a0[3] + a1[3] + a2[3] + a3[3];
      float cn = sigf_(gf) * creg + sigf_(gi) * tanhf_(gg);
      float hn = sigf_(go) * tanhf_(cn);
      creg = cn;
      pub_h(P.xc2 + (size_t)((t + 1) * 32 + gb) * KP + U0 + wv * 4, hn, vu, kq);
      if (t == T_ - 1 && vu) { P.oh1[gb * 1150 + un] = hn; P.oc1[gb * 1150 + un] = cn; }
      asm volatile("s_waitcnt vmcnt(0)" ::: "memory");
      __syncthreads();
      if (tid == 0) AGENT_ST(&f1[(gid * 2 + hf) * 16], t + 2);
    }
  } else {  // ---------------- L2 combined (input projection + recurrence) ----------------
    constexpr int KTA = 36, KPA = 1152, KTB = 13, KPB = 416;
    const int idx = bid - 216, hf = idx & 1, gid = idx >> 1, U0 = gid * 32;
    const int gb = hf * 16 + lm, un = U0 + wv * 4 + kq;
    const bool vu = un < 400;
    bf16x8 awi[KTA];
    load_aw<KTA>(P.wih2, 400, U0, wv, lm, kq, awi);
    bf16x8 awh[KTB];
    load_aw<KTB>(P.whh2, 400, U0, wv, lm, kq, awh);
    f32x4 bini = {0.f, 0.f, 0.f, 0.f};
    if (vu) {
#pragma unroll
      for (int g = 0; g < 4; ++g) bini[g] = P.bih2[g * 400 + un] + P.bhh2[g * 400 + un];
    }
    float creg = vu ? P.c0_2[gb * 400 + un] : 0.f;
    pub_h(P.xc3 + (size_t)gb * KPB + U0 + wv * 4, vu ? P.h0_2[gb * 400 + un] : 0.f, vu, kq);
    asm volatile("s_waitcnt vmcnt(0)" ::: "memory");
    __syncthreads();
    if (tid == 0) AGENT_ST(&f2[(gid * 2 + hf) * 16], 1);
    unsigned short* h1buf = sbuf;
    unsigned short* h2buf = sbuf + 16 * (KPA + 8);
    for (int t = 0; t < T_; ++t) {
      if (wv == 0) pollset(f1, hf, 36, t + 2);  // h1 output of step t
      else if (wv == 1) pollset(f2, hf, 13, t + 1);
      __syncthreads();
      stage2<KTA, KTB>(P.xc2 + (size_t)((t + 1) * 32 + hf * 16) * KPA,
                       P.xc3 + (size_t)(t * 32 + hf * 16) * KPB, h1buf, h2buf);
      __syncthreads();
      f32x4 a0 = bini, a1 = {0.f, 0.f, 0.f, 0.f}, a2 = {0.f, 0.f, 0.f, 0.f},
            a3 = {0.f, 0.f, 0.f, 0.f};
      mm4<KTA>(awi, h1buf, lm, kq, a0, a1, a2, a3);
      mm4<KTB>(awh, h2buf, lm, kq, a0, a1, a2, a3);
      float gi = a0[0] + a1[0] + a2[0] + a3[0], gf = a0[1] + a1[1] + a2[1] + a3[1];
      float gg = a0[2] + a1[2] + a2[2] + a3[2], go = a0[3] + a1[3] + a2[3] + a3[3];
      float cn = sigf_(gf) * creg + sigf_(gi) * tanhf_(gg);
      float hn = sigf_(go) * tanhf_(cn);
      creg = cn;
      pub_h(P.xc3 + (size_t)((t + 1) * 32 + gb) * KPB + U0 + wv * 4, hn, vu, kq);
      if (t == T_ - 1 && vu) { P.oh2[gb * 400 + un] = hn; P.oc2[gb * 400 + un] = cn; }
      asm volatile("s_waitcnt vmcnt(0)" ::: "memory");
      __syncthreads();
      if (tid == 0) AGENT_ST(&f2[(gid * 2 + hf) * 16], t + 2);
    }
  }
}

extern "C" void kernel_launch(void* const* d_in, const int* in_sizes, int n_in, void* d_out,
                              int out_size, void* d_ws, size_t ws_size, hipStream_t stream) {
  const int* input = (const int*)d_in[0];
  const float* emb_W = (const float*)d_in[1];
  const float* final_b = (const float*)d_in[2];

  struct L {
    const float *Wih, *Whh, *bih, *bhh, *h0, *c0;
  };
  L ls[3];
  ls[0] = {(const float*)d_in[3],  (const float*)d_in[4],  (const float*)d_in[5],
           (const float*)d_in[6],  (const float*)d_in[7],  (const float*)d_in[8]};
  ls[1] = {(const float*)d_in[9],  (const float*)d_in[10], (const float*)d_in[11],
           (const float*)d_in[12], (const float*)d_in[13], (const float*)d_in[14]};
  ls[2] = {(const float*)d_in[15], (const float*)d_in[16], (const float*)d_in[17],
           (const float*)d_in[18], (const float*)d_in[19], (const float*)d_in[20]};

  // ---- workspace layout ----
  char* base = (char*)d_ws;
  int* flags = (int*)base;                              // 64KB region
  float* xg0 = (float*)(base + 65536);                  // [4096][4608]
  float* ring = xg0 + (size_t)4096 * 4608;              // [16][32][4608]
  unsigned short* embbf = (unsigned short*)(ring + (size_t)16 * 32 * 4608);
  unsigned short* w0 = embbf + (size_t)33280 * 416;     // Wih0 [4608][416]
  unsigned short* wih1 = w0 + (size_t)4608 * 416;       // [4608][1152]
  unsigned short* whh0 = wih1 + (size_t)4608 * 1152;    // [4600][1152]
  unsigned short* whh1 = whh0 + (size_t)4600 * 1152;    // [4600][1152]
  unsigned short* wih2 = whh1 + (size_t)4600 * 1152;    // [1600][1152]
  unsigned short* whh2 = wih2 + (size_t)1600 * 1152;    // [1600][416]
  unsigned short* xemb = whh2 + (size_t)1600 * 416;     // [4096][416]
  unsigned short* xc1 = xemb + (size_t)4096 * 416;      // [4128][1152]
  unsigned short* xc2 = xc1 + (size_t)4128 * 1152;      // [4128][1152]
  unsigned short* xc3 = xc2 + (size_t)4128 * 1152;      // [4128][416]
  float* out = (float*)d_out;

  hipMemsetAsync(flags, 0, 65536, stream);

  // ---- merged weight conversions (1 launch) ----
  {
    CJobs J;
    long b = 0;
    auto add = [&](int i, const float* in, unsigned short* o, int N, int K, int Kp) {
      J.j[i] = {in, o, N, K, Kp, b};
      b += (long)((N + (Kp > K ? (Kp - K + (K - N % 1)) : 0), 0));  // placeholder, fixed below
    };
    (void)add;
    // explicit table (out rows are Npad x Kp; totals = Npad*Kp)
    J.j[0] = {emb_W, embbf, V_, E_, 416, 0};
    long t0 = (long)33280 * 416;
    J.j[1] = {ls[0].Wih, w0, 4600, 400, 416, t0};
    long t1 = t0 + (long)4608 * 416;
    J.j[2] = {ls[1].Wih, wih1, 4600, 1150, 1152, t1};
    long t2 = t1 + (long)4608 * 1152;
    J.j[3] = {ls[0].Whh, whh0, 4600, 1150, 1152, t2};
    long t3 = t2 + (long)4600 * 1152;
    J.j[4] = {ls[1].Whh, whh1, 4600, 1150, 1152, t3};
    long t4 = t3 + (long)4600 * 1152;
    J.j[5] = {ls[2].Wih, wih2, 1600, 1150, 1152, t4};
    long t5 = t4 + (long)1600 * 1152;
    J.j[6] = {ls[2].Whh, whh2, 1600, 400, 416, t5};
    J.total = t5 + (long)1600 * 416;
    convAll<<<8192, 256, 0, stream>>>(J);
  }
  embed_kernel<<<(T_ * B_ * 416 + 255) / 256, 256, 0, stream>>>(input, emb_W, xemb);

  long o = (long)T_ * B_ * V_;
  float* oh0 = out + o;
  float* oc0 = oh0 + 32 * 1150;
  float* oh1 = oc0 + 32 * 1150;
  float* oc1 = oh1 + 32 * 1150;
  float* oh2 = oc1 + 32 * 1150;
  float* oc2 = oh2 + 32 * 400;

  // ---- L0 input projection ----
  gemm_bf16<<<dim3(36, 32), 256, 0, stream>>>(xemb, w0, ls[0].bih, ls[0].bhh, xg0, 4096, 416, 4608,
                                              4600, 1150, 0);

  // ---- fused pipelined recurrence ----
  FP P;
  P.xg0 = xg0;
  P.ring = ring;
  P.whh0 = whh0;
  P.wih1 = wih1;
  P.whh1 = whh1;
  P.wih2 = wih2;
  P.whh2 = whh2;
  P.h0_0 = ls[0].h0;
  P.c0_0 = ls[0].c0;
  P.h0_1 = ls[1].h0;
  P.c0_1 = ls[1].c0;
  P.h0_2 = ls[2].h0;
  P.c0_2 = ls[2].c0;
  P.bih1 = ls[1].bih;
  P.bhh1 = ls[1].bhh;
  P.bih2 = ls[2].bih;
  P.bhh2 = ls[2].bhh;
  P.xc1 = xc1;
  P.xc2 = xc2;
  P.xc3 = xc3;
  P.oh0 = oh0;
  P.oc0 = oc0;
  P.oh1 = oh1;
  P.oc1 = oc1;
  P.oh2 = oh2;
  P.oc2 = oc2;
  P.flags = flags;
  fused_lstm<<<242, 512, 0, stream>>>(P);

  // ---- tied decoder (XCD-swizzled flat grid: 264 n-tiles x 32 m-tiles) ----
  gemm_bf16<<<8448, 256, 0, stream>>>(xc3 + (size_t)32 * 416, embbf, final_b, nullptr, out, 4096,
                                      416, V_, V_, 0, 1);
}

// Round 9
// 1576.106 us; speedup vs baseline: 1.0849x; 1.0849x over previous
//
#include <hip/hip_runtime.h>
#include <math.h>

#define T_ 128
#define B_ 32
#define V_ 33278
#define E_ 400

typedef __bf16 bf16x8 __attribute__((ext_vector_type(8)));
typedef float f32x4 __attribute__((ext_vector_type(4)));

#define AGENT_LD(p) __hip_atomic_load((p), __ATOMIC_RELAXED, __HIP_MEMORY_SCOPE_AGENT)
#define AGENT_ST(p, v) __hip_atomic_store((p), (v), __ATOMIC_RELAXED, __HIP_MEMORY_SCOPE_AGENT)

__device__ __forceinline__ float exp2f_(float x) {
  float r;
  asm("v_exp_f32 %0, %1" : "=v"(r) : "v"(x));
  return r;
}
__device__ __forceinline__ float rcpf_(float x) {
  float r;
  asm("v_rcp_f32 %0, %1" : "=v"(r) : "v"(x));
  return r;
}
__device__ __forceinline__ float sigf_(float x) { return rcpf_(1.0f + exp2f_(-1.44269504f * x)); }
__device__ __forceinline__ float tanhf_(float x) {
  float t = exp2f_(2.88539008f * x);
  return 1.0f - 2.0f * rcpf_(t + 1.0f);
}

__device__ __forceinline__ unsigned short f2bf(float f) {
  unsigned u = __float_as_uint(f);
  unsigned lsb = (u >> 16) & 1;
  return (unsigned short)((u + 0x7FFFu + lsb) >> 16);
}

__device__ __forceinline__ void gload16(const unsigned short* g, unsigned short* l) {
  __builtin_amdgcn_global_load_lds((const __attribute__((address_space(1))) void*)g,
                                   (__attribute__((address_space(3))) void*)l, 16, 0, 0);
}

// ---------------- embedding gather -> bf16 padded [T*B][416] ----------------
__global__ void embed_kernel(const int* __restrict__ idx, const float* __restrict__ W,
                             unsigned short* __restrict__ x) {
  int i = blockIdx.x * blockDim.x + threadIdx.x;
  if (i >= T_ * B_ * 416) return;
  int k = i % 416;
  int tb = i / 416;
  x[i] = (k < E_) ? f2bf(W[(size_t)idx[tb] * E_ + k]) : 0;
}

// ---------------- fp32 -> bf16 weight conversion with padding ----------------
__global__ void convW(const float* __restrict__ in, unsigned short* __restrict__ out, int N, int K,
                      int Kp, long total) {
  long i = (long)blockIdx.x * blockDim.x + threadIdx.x;
  if (i >= total) return;
  int k = (int)(i % Kp);
  long n = i / Kp;
  out[i] = (n < N && k < K) ? f2bf(in[n * (long)K + k]) : 0;
}

// ---------------- bf16 MFMA GEMM: C[M,N] = A[M,Kp] * B[N,Kp]^T + bias ----------------
// Epilogue remap (gateN>0): n (gate-major g*gateN+u) -> col = u*4 + g  (unit-major xg)
__global__ __launch_bounds__(256) void gemm_bf16(const unsigned short* __restrict__ A,
                                                 const unsigned short* __restrict__ B,
                                                 const float* __restrict__ bias0,
                                                 const float* __restrict__ bias1,
                                                 float* __restrict__ C, int M, int Kp, int ldc,
                                                 int realN, int gateN) {
  __shared__ __align__(16) unsigned short lsA[4 * 128 * 8];
  __shared__ __align__(16) unsigned short lsB[4 * 128 * 8];
  const int tid = threadIdx.x;
  const int lane = tid & 63;
  const int w = tid >> 6;
  const int wm = (w >> 1) * 64;
  const int wn = (w & 1) * 64;
  const int lr = lane & 15;
  const int kq = lane >> 4;
  const int m0 = blockIdx.y * 128;
  const int n0 = blockIdx.x * 128;

  f32x4 acc[4][4] = {};

  const int kiters = Kp >> 5;
  for (int kt = 0; kt < kiters; ++kt) {
    const int k0 = kt << 5;
#pragma unroll
    for (int q = 0; q < 2; ++q) {
      int s = w + q * 4;
      int kc = s >> 1, rb = (s & 1) * 64;
      gload16(A + (size_t)(m0 + rb + lane) * Kp + k0 + kc * 8, lsA + s * 512);
      gload16(B + (size_t)(n0 + rb + lane) * Kp + k0 + kc * 8, lsB + s * 512);
    }
    __syncthreads();

    bf16x8 af[4], bf[4];
#pragma unroll
    for (int mf = 0; mf < 4; ++mf)
      af[mf] = *(const bf16x8*)&lsA[(kq * 128 + wm + mf * 16 + lr) * 8];
#pragma unroll
    for (int nf = 0; nf < 4; ++nf)
      bf[nf] = *(const bf16x8*)&lsB[(kq * 128 + wn + nf * 16 + lr) * 8];
#pragma unroll
    for (int mf = 0; mf < 4; ++mf)
#pragma unroll
      for (int nf = 0; nf < 4; ++nf)
        acc[mf][nf] = __builtin_amdgcn_mfma_f32_16x16x32_bf16(af[mf], bf[nf], acc[mf][nf], 0, 0, 0);
    __syncthreads();
  }

#pragma unroll
  for (int nf = 0; nf < 4; ++nf) {
    int n = n0 + wn + nf * 16 + lr;
    if (n >= realN) continue;
    float bsum = 0.0f;
    if (bias0) bsum += bias0[n];
    if (bias1) bsum += bias1[n];
    int col = n;
    if (gateN > 0) {
      int g = (n >= gateN) + (n >= 2 * gateN) + (n >= 3 * gateN);
      int u = n - g * gateN;
      col = u * 4 + g;
    }
#pragma unroll
    for (int mf = 0; mf < 4; ++mf) {
      int mbase = m0 + wm + mf * 16 + kq * 4;
#pragma unroll
      for (int r = 0; r < 4; ++r) C[(size_t)(mbase + r) * ldc + col] = acc[mf][nf][r] + bsum;
    }
  }
}

// ================= fused pipelined 3-layer LSTM recurrence =================
// Roles by blockIdx.x: [0,72) L0 rec | [72,144) L1 input-helper | [144,216) L1 rec
// | [216,242) L2 combined. 242 blocks x 512 thr, 1 block/CU.
// h-chains: write-once; agent u64 publish -> flag; consumers stage with NORMAL
// uint4 loads (L2 path; validated r7/r8). xg buffer OVERLAY: helper writes xg1(t)
// into xg0 slot t (dead after L0 step t, guaranteed by f0>=t+2); those lines are
// stale-cached in L2 from L0's normal reads, so L1 MUST read them agent-scope.
// All poll loops use s_sleep backoff to cut MALL poll traffic (r6 lesson).

struct FP {
  float* xg;  // [T*32][4608] fp32 unit-major: slot t = xg0(t), overwritten later by xg1(t)
  const unsigned short *whh0, *wih1, *whh1, *wih2, *whh2;
  const float *h0_0, *c0_0, *h0_1, *c0_1, *h0_2, *c0_2;
  const float *bih1, *bhh1, *bih2, *bhh2;
  unsigned short *xc1, *xc2, *xc3;  // chains: [(1+T)*32][KP]
  float *oh0, *oc0, *oh1, *oc1, *oh2, *oc2;
  int* flags;
};

__device__ __forceinline__ void pollset(const int* f, int hf, int n, int tgt) {
  int lane = threadIdx.x & 63;
  for (;;) {
    int v = (lane < n) ? AGENT_LD(&f[((lane << 1) + hf) * 16]) : tgt;
    if (__all(v >= tgt)) break;
    __builtin_amdgcn_s_sleep(1);
  }
}

__device__ __forceinline__ void pollone(const int* f, int tgt) {
  for (;;) {
    int v = AGENT_LD(f);
    if (__all(v >= tgt)) break;
    __builtin_amdgcn_s_sleep(1);
  }
}

// normal-load staging (L2 path): slab rows are 16B-aligned, write-once
template <int KT>
__device__ __forceinline__ void stage(const unsigned short* slab, unsigned short* lds) {
  constexpr int KP = KT * 32, KPP = KP + 8, C16 = KP / 8, NCH = 16 * C16;
  constexpr int NIT = (NCH + 511) / 512;
  const int tid = threadIdx.x;
  uint4 d[NIT];
#pragma unroll
  for (int i = 0; i < NIT; ++i) {
    int c = tid + i * 512;
    if (c < NCH) d[i] = *(const uint4*)(slab + (size_t)(c / C16) * KP + (c % C16) * 8);
  }
#pragma unroll
  for (int i = 0; i < NIT; ++i) {
    int c = tid + i * 512;
    if (c < NCH) *(uint4*)&lds[(c / C16) * KPP + (c % C16) * 8] = d[i];
  }
}

// combined two-slab stage: issue ALL loads before committing either
template <int KTA, int KTB>
__device__ __forceinline__ void stage2(const unsigned short* slabA, const unsigned short* slabB,
                                       unsigned short* ldsA, unsigned short* ldsB) {
  constexpr int KPA = KTA * 32, KPPA = KPA + 8, CA = KPA / 8, NA = 16 * CA;
  constexpr int NITA = (NA + 511) / 512;
  constexpr int KPB = KTB * 32, KPPB = KPB + 8, CB = KPB / 8, NB = 16 * CB;
  constexpr int NITB = (NB + 511) / 512;
  const int tid = threadIdx.x;
  uint4 dA[NITA], dB[NITB];
#pragma unroll
  for (int i = 0; i < NITA; ++i) {
    int c = tid + i * 512;
    if (c < NA) dA[i] = *(const uint4*)(slabA + (size_t)(c / CA) * KPA + (c % CA) * 8);
  }
#pragma unroll
  for (int i = 0; i < NITB; ++i) {
    int c = tid + i * 512;
    if (c < NB) dB[i] = *(const uint4*)(slabB + (size_t)(c / CB) * KPB + (c % CB) * 8);
  }
#pragma unroll
  for (int i = 0; i < NITA; ++i) {
    int c = tid + i * 512;
    if (c < NA) *(uint4*)&ldsA[(c / CA) * KPPA + (c % CA) * 8] = dA[i];
  }
#pragma unroll
  for (int i = 0; i < NITB; ++i) {
    int c = tid + i * 512;
    if (c < NB) *(uint4*)&ldsB[(c / CB) * KPPB + (c % CB) * 8] = dB[i];
  }
}

template <int KT>
__device__ __forceinline__ void load_aw(const unsigned short* w, int dh, int U0, int wv, int lm,
                                        int kq, bf16x8* aw) {
  const int ga = lm & 3, ula = lm >> 2;
  const int ua = U0 + wv * 4 + ula;
  const unsigned short* wr = w + (size_t)(ga * dh + (ua < dh ? ua : 0)) * (KT * 32);
#pragma unroll
  for (int kt = 0; kt < KT; ++kt) aw[kt] = *(const bf16x8*)&wr[kt * 32 + kq * 8];
}

template <int KT>
__device__ __forceinline__ void mm4(const bf16x8* aw, const unsigned short* lds, int lm, int kq,
                                    f32x4& a0, f32x4& a1, f32x4& a2, f32x4& a3) {
  constexpr int KPP = KT * 32 + 8;
  const unsigned short* rp = lds + lm * KPP + kq * 8;
#pragma unroll
  for (int kt = 0; kt < KT; kt += 4) {
    a0 = __builtin_amdgcn_mfma_f32_16x16x32_bf16(aw[kt], *(const bf16x8*)&rp[kt * 32], a0, 0, 0, 0);
    if (kt + 1 < KT)
      a1 = __builtin_amdgcn_mfma_f32_16x16x32_bf16(aw[kt + 1], *(const bf16x8*)&rp[(kt + 1) * 32],
                                                   a1, 0, 0, 0);
    if (kt + 2 < KT)
      a2 = __builtin_amdgcn_mfma_f32_16x16x32_bf16(aw[kt + 2], *(const bf16x8*)&rp[(kt + 2) * 32],
                                                   a2, 0, 0, 0);
    if (kt + 3 < KT)
      a3 = __builtin_amdgcn_mfma_f32_16x16x32_bf16(aw[kt + 3], *(const bf16x8*)&rp[(kt + 3) * 32],
                                                   a3, 0, 0, 0);
  }
}

__device__ __forceinline__ void pub_h(unsigned short* dst, float hn, bool vu, int kq) {
  unsigned hv = vu ? (unsigned)f2bf(hn) : 0u;
  unsigned t16 = (unsigned)__shfl_xor((int)hv, 16);
  unsigned v32 = (kq & 1) ? (t16 | (hv << 16)) : (hv | (t16 << 16));
  unsigned o32 = (unsigned)__shfl_xor((int)v32, 32);
  if (kq == 0)
    AGENT_ST((unsigned long long*)dst, (unsigned long long)v32 | ((unsigned long long)o32 << 32));
}

__global__ __launch_bounds__(512, 2) void fused_lstm(FP P) {
  __shared__ __align__(16) unsigned short sbuf[16 * 1160 + 16 * 424];
  const int tid = threadIdx.x;
  const int lane = tid & 63;
  const int wv = tid >> 6;
  const int lm = lane & 15;
  const int kq = lane >> 4;
  const int bid = blockIdx.x;
  int* f0 = P.flags;
  int* fh = P.flags + 72 * 16;
  int* f1 = P.flags + 144 * 16;
  int* f2 = P.flags + 216 * 16;

  if (bid < 72) {  // ---------------- L0 recurrence ----------------
    constexpr int KT = 36, KP = 1152;
    const int hf = bid & 1, gid = bid >> 1, U0 = gid * 32;
    const int gb = hf * 16 + lm, un = U0 + wv * 4 + kq;
    const bool vu = un < 1150;
    bf16x8 aw[KT];
    load_aw<KT>(P.whh0, 1150, U0, wv, lm, kq, aw);
    float creg = vu ? P.c0_0[gb * 1150 + un] : 0.f;
    pub_h(P.xc1 + (size_t)gb * KP + U0 + wv * 4, vu ? P.h0_0[gb * 1150 + un] : 0.f, vu, kq);
    asm volatile("s_waitcnt vmcnt(0)" ::: "memory");
    __syncthreads();
    if (tid == 0) AGENT_ST(&f0[(gid * 2 + hf) * 16], 1);
    for (int t = 0; t < T_; ++t) {
      f32x4 cinit = *(const f32x4*)&P.xg[(size_t)(t * 32 + gb) * 4608 + un * 4];
      if (wv == 0) pollset(f0, hf, 36, t + 1);
      __syncthreads();
      stage<KT>(P.xc1 + (size_t)(t * 32 + hf * 16) * KP, sbuf);
      __syncthreads();
      f32x4 a0 = cinit, a1 = {0.f, 0.f, 0.f, 0.f}, a2 = {0.f, 0.f, 0.f, 0.f},
            a3 = {0.f, 0.f, 0.f, 0.f};
      mm4<KT>(aw, sbuf, lm, kq, a0, a1, a2, a3);
      float gi = a0[0] + a1[0] + a2[0] + a3[0], gf = a0[1] + a1[1] + a2[1] + a3[1];
      float gg = a0[2] + a1[2] + a2[2] + a3[2], go = a0[3] + a1[3] + a2[3] + a3[3];
      float cn = sigf_(gf) * creg + sigf_(gi) * tanhf_(gg);
      float hn = sigf_(go) * tanhf_(cn);
      creg = cn;
      pub_h(P.xc1 + (size_t)((t + 1) * 32 + gb) * KP + U0 + wv * 4, hn, vu, kq);
      if (t == T_ - 1 && vu) { P.oh0[gb * 1150 + un] = hn; P.oc0[gb * 1150 + un] = cn; }
      asm volatile("s_waitcnt vmcnt(0)" ::: "memory");
      __syncthreads();
      if (tid == 0) AGENT_ST(&f0[(gid * 2 + hf) * 16], t + 2);
    }
  } else if (bid < 144) {  // ---------------- L1 input-projection helper ----------------
    constexpr int KT = 36, KP = 1152;
    const int idx = bid - 72, hf = idx & 1, gid = idx >> 1, U0 = gid * 32;
    const int gb = hf * 16 + lm, un = U0 + wv * 4 + kq;
    const bool vu = un < 1150;
    bf16x8 aw[KT];
    load_aw<KT>(P.wih1, 1150, U0, wv, lm, kq, aw);
    f32x4 bini = {0.f, 0.f, 0.f, 0.f};
    if (vu) {
#pragma unroll
      for (int g = 0; g < 4; ++g) bini[g] = P.bih1[g * 1150 + un] + P.bhh1[g * 1150 + un];
    }
    for (int t = 0; t < T_; ++t) {
      if (wv == 0) pollset(f0, hf, 36, t + 2);  // h0 output of step t = chain0 row t+1
      __syncthreads();
      stage<KT>(P.xc1 + (size_t)((t + 1) * 32 + hf * 16) * KP, sbuf);
      __syncthreads();
      f32x4 a0 = bini, a1 = {0.f, 0.f, 0.f, 0.f}, a2 = {0.f, 0.f, 0.f, 0.f},
            a3 = {0.f, 0.f, 0.f, 0.f};
      mm4<KT>(aw, sbuf, lm, kq, a0, a1, a2, a3);
      float r0 = a0[0] + a1[0] + a2[0] + a3[0], r1 = a0[1] + a1[1] + a2[1] + a3[1];
      float r2 = a0[2] + a1[2] + a2[2] + a3[2], r3 = a0[3] + a1[3] + a2[3] + a3[3];
      // overlay write: xg slot t was consumed by L0 at its step t (f0>=t+2 proves it)
      unsigned long long* dst =
          (unsigned long long*)(P.xg + (size_t)(t * 32 + gb) * 4608 + un * 4);
      AGENT_ST(dst, ((unsigned long long)__float_as_uint(r1) << 32) | __float_as_uint(r0));
      AGENT_ST(dst + 1, ((unsigned long long)__float_as_uint(r3) << 32) | __float_as_uint(r2));
      asm volatile("s_waitcnt vmcnt(0)" ::: "memory");
      __syncthreads();
      if (tid == 0) AGENT_ST(&fh[(gid * 2 + hf) * 16], t + 1);
    }
  } else if (bid < 216) {  // ---------------- L1 recurrence ----------------
    constexpr int KT = 36, KP = 1152;
    const int idx = bid - 144, hf = idx & 1, gid = idx >> 1, U0 = gid * 32;
    const int gb = hf * 16 + lm, un = U0 + wv * 4 + kq;
    const bool vu = un < 1150;
    bf16x8 aw[KT];
    load_aw<KT>(P.whh1, 1150, U0, wv, lm, kq, aw);
    float creg = vu ? P.c0_1[gb * 1150 + un] : 0.f;
    pub_h(P.xc2 + (size_t)gb * KP + U0 + wv * 4, vu ? P.h0_1[gb * 1150 + un] : 0.f, vu, kq);
    asm volatile("s_waitcnt vmcnt(0)" ::: "memory");
    __syncthreads();
    if (tid == 0) AGENT_ST(&f1[(gid * 2 + hf) * 16], 1);
    for (int t = 0; t < T_; ++t) {
      if (wv == 0) pollset(f1, hf, 36, t + 1);
      else if (wv == 1) pollone(&fh[(gid * 2 + hf) * 16], t + 1);
      __syncthreads();
      stage<KT>(P.xc2 + (size_t)(t * 32 + hf * 16) * KP, sbuf);
      // xg1(t): agent read (overlay lines are stale in L2 from L0's normal reads)
      const unsigned long long* rp =
          (const unsigned long long*)(P.xg + (size_t)(t * 32 + gb) * 4608 + un * 4);
      unsigned long long q0 = AGENT_LD(rp), q1 = AGENT_LD(rp + 1);
      __syncthreads();
      f32x4 a0, a1 = {0.f, 0.f, 0.f, 0.f}, a2 = {0.f, 0.f, 0.f, 0.f}, a3 = {0.f, 0.f, 0.f, 0.f};
      a0[0] = __uint_as_float((unsigned)q0);
      a0[1] = __uint_as_float((unsigned)(q0 >> 32));
      a0[2] = __uint_as_float((unsigned)q1);
      a0[3] = __uint_as_float((unsigned)(q1 >> 32));
      mm4<KT>(aw, sbuf, lm, kq, a0, a1, a2, a3);
      float gi = a0[0] + a1[0] + a2[0] + a3[0], gf = a0[1] + a1[1] + a2[1] + a3[1];
      float gg = a0[2] + a1[2] + a2[2] + a3[2], go = a0[3] + a1[3] + a2[3] + a3[3];
      float cn = sigf_(gf) * creg + sigf_(gi) * tanhf_(gg);
      float hn = sigf_(go) * tanhf_(cn);
      creg = cn;
      pub_h(P.xc2 + (size_t)((t + 1) * 32 + gb) * KP + U0 + wv * 4, hn, vu, kq);
      if (t == T_ - 1 && vu) { P.oh1[gb * 1150 + un] = hn; P.oc1[gb * 1150 + un] = cn; }
      asm volatile("s_waitcnt vmcnt(0)" ::: "memory");
      __syncthreads();
      if (tid == 0) AGENT_ST(&f1[(gid * 2 + hf) * 16], t + 2);
    }
  } else {  // ---------------- L2 combined (input projection + recurrence) ----------------
    constexpr int KTA = 36, KPA = 1152, KTB = 13, KPB = 416;
    const int idx = bid - 216, hf = idx & 1, gid = idx >> 1, U0 = gid * 32;
    const int gb = hf * 16 + lm, un = U0 + wv * 4 + kq;
    const bool vu = un < 400;
    bf16x8 awi[KTA];
    load_aw<KTA>(P.wih2, 400, U0, wv, lm, kq, awi);
    bf16x8 awh[KTB];
    load_aw<KTB>(P.whh2, 400, U0, wv, lm, kq, awh);
    f32x4 bini = {0.f, 0.f, 0.f, 0.f};
    if (vu) {
#pragma unroll
      for (int g = 0; g < 4; ++g) bini[g] = P.bih2[g * 400 + un] + P.bhh2[g * 400 + un];
    }
    float creg = vu ? P.c0_2[gb * 400 + un] : 0.f;
    pub_h(P.xc3 + (size_t)gb * KPB + U0 + wv * 4, vu ? P.h0_2[gb * 400 + un] : 0.f, vu, kq);
    asm volatile("s_waitcnt vmcnt(0)" ::: "memory");
    __syncthreads();
    if (tid == 0) AGENT_ST(&f2[(gid * 2 + hf) * 16], 1);
    unsigned short* h1buf = sbuf;
    unsigned short* h2buf = sbuf + 16 * (KPA + 8);
    for (int t = 0; t < T_; ++t) {
      if (wv == 0) pollset(f1, hf, 36, t + 2);  // h1 output of step t
      else if (wv == 1) pollset(f2, hf, 13, t + 1);
      __syncthreads();
      stage2<KTA, KTB>(P.xc2 + (size_t)((t + 1) * 32 + hf * 16) * KPA,
                       P.xc3 + (size_t)(t * 32 + hf * 16) * KPB, h1buf, h2buf);
      __syncthreads();
      f32x4 a0 = bini, a1 = {0.f, 0.f, 0.f, 0.f}, a2 = {0.f, 0.f, 0.f, 0.f},
            a3 = {0.f, 0.f, 0.f, 0.f};
      mm4<KTA>(awi, h1buf, lm, kq, a0, a1, a2, a3);
      mm4<KTB>(awh, h2buf, lm, kq, a0, a1, a2, a3);
      float gi = a0[0] + a1[0] + a2[0] + a3[0], gf = a0[1] + a1[1] + a2[1] + a3[1];
      float gg = a0[2] + a1[2] + a2[2] + a3[2], go = a0[3] + a1[3] + a2[3] + a3[3];
      float cn = sigf_(gf) * creg + sigf_(gi) * tanhf_(gg);
      float hn = sigf_(go) * tanhf_(cn);
      creg = cn;
      pub_h(P.xc3 + (size_t)((t + 1) * 32 + gb) * KPB + U0 + wv * 4, hn, vu, kq);
      if (t == T_ - 1 && vu) { P.oh2[gb * 400 + un] = hn; P.oc2[gb * 400 + un] = cn; }
      asm volatile("s_waitcnt vmcnt(0)" ::: "memory");
      __syncthreads();
      if (tid == 0) AGENT_ST(&f2[(gid * 2 + hf) * 16], t + 2);
    }
  }
}

extern "C" void kernel_launch(void* const* d_in, const int* in_sizes, int n_in, void* d_out,
                              int out_size, void* d_ws, size_t ws_size, hipStream_t stream) {
  const int* input = (const int*)d_in[0];
  const float* emb_W = (const float*)d_in[1];
  const float* final_b = (const float*)d_in[2];

  struct L {
    const float *Wih, *Whh, *bih, *bhh, *h0, *c0;
  };
  L ls[3];
  ls[0] = {(const float*)d_in[3],  (const float*)d_in[4],  (const float*)d_in[5],
           (const float*)d_in[6],  (const float*)d_in[7],  (const float*)d_in[8]};
  ls[1] = {(const float*)d_in[9],  (const float*)d_in[10], (const float*)d_in[11],
           (const float*)d_in[12], (const float*)d_in[13], (const float*)d_in[14]};
  ls[2] = {(const float*)d_in[15], (const float*)d_in[16], (const float*)d_in[17],
           (const float*)d_in[18], (const float*)d_in[19], (const float*)d_in[20]};

  // ---- workspace layout ----
  char* base = (char*)d_ws;
  int* flags = (int*)base;                              // 64KB region
  float* xg0 = (float*)(base + 65536);                  // [4096][4608] (overlaid by xg1)
  unsigned short* embbf = (unsigned short*)(xg0 + (size_t)4096 * 4608);
  unsigned short* w0 = embbf + (size_t)33280 * 416;     // Wih0 [4608][416]
  unsigned short* wih1 = w0 + (size_t)4608 * 416;       // [4608][1152]
  unsigned short* whh0 = wih1 + (size_t)4608 * 1152;    // [4600][1152]
  unsigned short* whh1 = whh0 + (size_t)4600 * 1152;    // [4600][1152]
  unsigned short* wih2 = whh1 + (size_t)4600 * 1152;    // [1600][1152]
  unsigned short* whh2 = wih2 + (size_t)1600 * 1152;    // [1600][416]
  unsigned short* xemb = whh2 + (size_t)1600 * 416;     // [4096][416]
  unsigned short* xc1 = xemb + (size_t)4096 * 416;      // [4128][1152]
  unsigned short* xc2 = xc1 + (size_t)4128 * 1152;      // [4128][1152]
  unsigned short* xc3 = xc2 + (size_t)4128 * 1152;      // [4128][416]
  float* out = (float*)d_out;

  hipMemsetAsync(flags, 0, 65536, stream);

  // ---- conversions (separate launches; r8's merged kernel regressed) ----
  {
    long tot = (long)33280 * 416;
    convW<<<(unsigned)((tot + 255) / 256), 256, 0, stream>>>(emb_W, embbf, V_, E_, 416, tot);
  }
  {
    long tot = (long)4608 * 416;
    convW<<<(unsigned)((tot + 255) / 256), 256, 0, stream>>>(ls[0].Wih, w0, 4600, 400, 416, tot);
  }
  {
    long tot = (long)4608 * 1152;
    convW<<<(unsigned)((tot + 255) / 256), 256, 0, stream>>>(ls[1].Wih, wih1, 4600, 1150, 1152,
                                                             tot);
  }
  {
    long tot = (long)4600 * 1152;
    convW<<<(unsigned)((tot + 255) / 256), 256, 0, stream>>>(ls[0].Whh, whh0, 4600, 1150, 1152,
                                                             tot);
    convW<<<(unsigned)((tot + 255) / 256), 256, 0, stream>>>(ls[1].Whh, whh1, 4600, 1150, 1152,
                                                             tot);
  }
  {
    long tot = (long)1600 * 1152;
    convW<<<(unsigned)((tot + 255) / 256), 256, 0, stream>>>(ls[2].Wih, wih2, 1600, 1150, 1152,
                                                             tot);
  }
  {
    long tot = (long)1600 * 416;
    convW<<<(unsigned)((tot + 255) / 256), 256, 0, stream>>>(ls[2].Whh, whh2, 1600, 400, 416, tot);
  }
  embed_kernel<<<(T_ * B_ * 416 + 255) / 256, 256, 0, stream>>>(input, emb_W, xemb);

  long o = (long)T_ * B_ * V_;
  float* oh0 = out + o;
  float* oc0 = oh0 + 32 * 1150;
  float* oh1 = oc0 + 32 * 1150;
  float* oc1 = oh1 + 32 * 1150;
  float* oh2 = oc1 + 32 * 1150;
  float* oc2 = oh2 + 32 * 400;

  // ---- L0 input projection ----
  gemm_bf16<<<dim3(36, 32), 256, 0, stream>>>(xemb, w0, ls[0].bih, ls[0].bhh, xg0, 4096, 416, 4608,
                                              4600, 1150);

  // ---- fused pipelined recurrence ----
  FP P;
  P.xg = xg0;
  P.whh0 = whh0;
  P.wih1 = wih1;
  P.whh1 = whh1;
  P.wih2 = wih2;
  P.whh2 = whh2;
  P.h0_0 = ls[0].h0;
  P.c0_0 = ls[0].c0;
  P.h0_1 = ls[1].h0;
  P.c0_1 = ls[1].c0;
  P.h0_2 = ls[2].h0;
  P.c0_2 = ls[2].c0;
  P.bih1 = ls[1].bih;
  P.bhh1 = ls[1].bhh;
  P.bih2 = ls[2].bih;
  P.bhh2 = ls[2].bhh;
  P.xc1 = xc1;
  P.xc2 = xc2;
  P.xc3 = xc3;
  P.oh0 = oh0;
  P.oc0 = oc0;
  P.oh1 = oh1;
  P.oc1 = oc1;
  P.oh2 = oh2;
  P.oc2 = oc2;
  P.flags = flags;
  fused_lstm<<<242, 512, 0, stream>>>(P);

  // ---- tied decoder ----
  gemm_bf16<<<dim3(260, 32), 256, 0, stream>>>(xc3 + (size_t)32 * 416, embbf, final_b, nullptr,
                                               out, 4096, 416, V_, V_, 0);
}

// Round 11
// 1517.975 us; speedup vs baseline: 1.1265x; 1.0383x over previous
//
#include <hip/hip_runtime.h>
#include <math.h>

#define T_ 128
#define B_ 32
#define V_ 33278
#define E_ 400

typedef __bf16 bf16x8 __attribute__((ext_vector_type(8)));
typedef float f32x4 __attribute__((ext_vector_type(4)));

#define AGENT_LD(p) __hip_atomic_load((p), __ATOMIC_RELAXED, __HIP_MEMORY_SCOPE_AGENT)
#define AGENT_ST(p, v) __hip_atomic_store((p), (v), __ATOMIC_RELAXED, __HIP_MEMORY_SCOPE_AGENT)

__device__ __forceinline__ float exp2f_(float x) {
  float r;
  asm("v_exp_f32 %0, %1" : "=v"(r) : "v"(x));
  return r;
}
__device__ __forceinline__ float rcpf_(float x) {
  float r;
  asm("v_rcp_f32 %0, %1" : "=v"(r) : "v"(x));
  return r;
}
__device__ __forceinline__ float sigf_(float x) { return rcpf_(1.0f + exp2f_(-1.44269504f * x)); }
__device__ __forceinline__ float tanhf_(float x) {
  float t = exp2f_(2.88539008f * x);
  return 1.0f - 2.0f * rcpf_(t + 1.0f);
}

__device__ __forceinline__ unsigned short f2bf(float f) {
  unsigned u = __float_as_uint(f);
  unsigned lsb = (u >> 16) & 1;
  return (unsigned short)((u + 0x7FFFu + lsb) >> 16);
}

__device__ __forceinline__ void gload16(const unsigned short* g, unsigned short* l) {
  __builtin_amdgcn_global_load_lds((const __attribute__((address_space(1))) void*)g,
                                   (__attribute__((address_space(3))) void*)l, 16, 0, 0);
}

// ---------------- embedding gather -> bf16 padded [T*B][416] ----------------
__global__ void embed_kernel(const int* __restrict__ idx, const float* __restrict__ W,
                             unsigned short* __restrict__ x) {
  int i = blockIdx.x * blockDim.x + threadIdx.x;
  if (i >= T_ * B_ * 416) return;
  int k = i % 416;
  int tb = i / 416;
  x[i] = (k < E_) ? f2bf(W[(size_t)idx[tb] * E_ + k]) : 0;
}

// ---------------- fp32 -> bf16 weight conversion with padding ----------------
__global__ void convW(const float* __restrict__ in, unsigned short* __restrict__ out, int N, int K,
                      int Kp, long total) {
  long i = (long)blockIdx.x * blockDim.x + threadIdx.x;
  if (i >= total) return;
  int k = (int)(i % Kp);
  long n = i / Kp;
  out[i] = (n < N && k < K) ? f2bf(in[n * (long)K + k]) : 0;
}

// ---------------- bf16 MFMA GEMM: C[M,N] = A[M,Kp] * B[N,Kp]^T + bias ----------------
// Epilogue remap (gateN>0): n (gate-major g*gateN+u) -> col = u*4 + g  (unit-major xg)
__global__ __launch_bounds__(256) void gemm_bf16(const unsigned short* __restrict__ A,
                                                 const unsigned short* __restrict__ B,
                                                 const float* __restrict__ bias0,
                                                 const float* __restrict__ bias1,
                                                 float* __restrict__ C, int M, int Kp, int ldc,
                                                 int realN, int gateN) {
  __shared__ __align__(16) unsigned short lsA[4 * 128 * 8];
  __shared__ __align__(16) unsigned short lsB[4 * 128 * 8];
  const int tid = threadIdx.x;
  const int lane = tid & 63;
  const int w = tid >> 6;
  const int wm = (w >> 1) * 64;
  const int wn = (w & 1) * 64;
  const int lr = lane & 15;
  const int kq = lane >> 4;
  const int m0 = blockIdx.y * 128;
  const int n0 = blockIdx.x * 128;

  f32x4 acc[4][4] = {};

  const int kiters = Kp >> 5;
  for (int kt = 0; kt < kiters; ++kt) {
    const int k0 = kt << 5;
#pragma unroll
    for (int q = 0; q < 2; ++q) {
      int s = w + q * 4;
      int kc = s >> 1, rb = (s & 1) * 64;
      gload16(A + (size_t)(m0 + rb + lane) * Kp + k0 + kc * 8, lsA + s * 512);
      gload16(B + (size_t)(n0 + rb + lane) * Kp + k0 + kc * 8, lsB + s * 512);
    }
    __syncthreads();

    bf16x8 af[4], bf[4];
#pragma unroll
    for (int mf = 0; mf < 4; ++mf)
      af[mf] = *(const bf16x8*)&lsA[(kq * 128 + wm + mf * 16 + lr) * 8];
#pragma unroll
    for (int nf = 0; nf < 4; ++nf)
      bf[nf] = *(const bf16x8*)&lsB[(kq * 128 + wn + nf * 16 + lr) * 8];
#pragma unroll
    for (int mf = 0; mf < 4; ++mf)
#pragma unroll
      for (int nf = 0; nf < 4; ++nf)
        acc[mf][nf] = __builtin_amdgcn_mfma_f32_16x16x32_bf16(af[mf], bf[nf], acc[mf][nf], 0, 0, 0);
    __syncthreads();
  }

#pragma unroll
  for (int nf = 0; nf < 4; ++nf) {
    int n = n0 + wn + nf * 16 + lr;
    if (n >= realN) continue;
    float bsum = 0.0f;
    if (bias0) bsum += bias0[n];
    if (bias1) bsum += bias1[n];
    int col = n;
    if (gateN > 0) {
      int g = (n >= gateN) + (n >= 2 * gateN) + (n >= 3 * gateN);
      int u = n - g * gateN;
      col = u * 4 + g;
    }
#pragma unroll
    for (int mf = 0; mf < 4; ++mf) {
      int mbase = m0 + wm + mf * 16 + kq * 4;
#pragma unroll
      for (int r = 0; r < 4; ++r) C[(size_t)(mbase + r) * ldc + col] = acc[mf][nf][r] + bsum;
    }
  }
}

// ================= fused pipelined 3-layer LSTM recurrence =================
// Roles: [0,72) L0 rec | [72,144) L1 helper | [144,216) L1 rec | [216,242) L2 |
// [242,246) flag AGGREGATORS (wave-0-only; one per {f0,f1}x{half}).
// Aggregators tight-poll the 36 producer flags of their set and publish a single
// epoch line at flags+4096 ints (DISJOINT from f0/fh/f1/f2: [0,3872) ints —
// r10's deadlock was agg@1024 colliding with f0 lines 64..67).
// Workers poll ONE line each -> ~20x less MALL poll traffic (r6/r9 lesson).
// h-chains write-once: agent u64 publish; consumers stage via NORMAL uint4 loads.
// xg overlay: helper writes xg1(t) over xg0 slot t (dead once f0>=t+2); L1 reads
// those lines agent-scope (stale in L2 from L0's normal reads).

struct FP {
  float* xg;  // [T*32][4608] fp32 unit-major: slot t = xg0(t), later xg1(t)
  const unsigned short *whh0, *wih1, *whh1, *wih2, *whh2;
  const float *h0_0, *c0_0, *h0_1, *c0_1, *h0_2, *c0_2;
  const float *bih1, *bhh1, *bih2, *bhh2;
  unsigned short *xc1, *xc2, *xc3;  // chains: [(1+T)*32][KP]
  float *oh0, *oc0, *oh1, *oc1, *oh2, *oc2;
  int* flags;
};

__device__ __forceinline__ void pollset(const int* f, int hf, int n, int tgt) {
  int lane = threadIdx.x & 63;
  for (;;) {
    int v = (lane < n) ? AGENT_LD(&f[((lane << 1) + hf) * 16]) : tgt;
    if (__all(v >= tgt)) break;
  }
}

__device__ __forceinline__ void pollone(const int* f, int tgt) {
  for (;;) {
    int v = AGENT_LD(f);
    if (__all(v >= tgt)) break;
  }
}

// normal-load staging (L2 path): slab rows are 16B-aligned, write-once
template <int KT>
__device__ __forceinline__ void stage(const unsigned short* slab, unsigned short* lds) {
  constexpr int KP = KT * 32, KPP = KP + 8, C16 = KP / 8, NCH = 16 * C16;
  constexpr int NIT = (NCH + 511) / 512;
  const int tid = threadIdx.x;
  uint4 d[NIT];
#pragma unroll
  for (int i = 0; i < NIT; ++i) {
    int c = tid + i * 512;
    if (c < NCH) d[i] = *(const uint4*)(slab + (size_t)(c / C16) * KP + (c % C16) * 8);
  }
#pragma unroll
  for (int i = 0; i < NIT; ++i) {
    int c = tid + i * 512;
    if (c < NCH) *(uint4*)&lds[(c / C16) * KPP + (c % C16) * 8] = d[i];
  }
}

// combined two-slab stage: issue ALL loads before committing either
template <int KTA, int KTB>
__device__ __forceinline__ void stage2(const unsigned short* slabA, const unsigned short* slabB,
                                       unsigned short* ldsA, unsigned short* ldsB) {
  constexpr int KPA = KTA * 32, KPPA = KPA + 8, CA = KPA / 8, NA = 16 * CA;
  constexpr int NITA = (NA + 511) / 512;
  constexpr int KPB = KTB * 32, KPPB = KPB + 8, CB = KPB / 8, NB = 16 * CB;
  constexpr int NITB = (NB + 511) / 512;
  const int tid = threadIdx.x;
  uint4 dA[NITA], dB[NITB];
#pragma unroll
  for (int i = 0; i < NITA; ++i) {
    int c = tid + i * 512;
    if (c < NA) dA[i] = *(const uint4*)(slabA + (size_t)(c / CA) * KPA + (c % CA) * 8);
  }
#pragma unroll
  for (int i = 0; i < NITB; ++i) {
    int c = tid + i * 512;
    if (c < NB) dB[i] = *(const uint4*)(slabB + (size_t)(c / CB) * KPB + (c % CB) * 8);
  }
#pragma unroll
  for (int i = 0; i < NITA; ++i) {
    int c = tid + i * 512;
    if (c < NA) *(uint4*)&ldsA[(c / CA) * KPPA + (c % CA) * 8] = dA[i];
  }
#pragma unroll
  for (int i = 0; i < NITB; ++i) {
    int c = tid + i * 512;
    if (c < NB) *(uint4*)&ldsB[(c / CB) * KPPB + (c % CB) * 8] = dB[i];
  }
}

template <int KT>
__device__ __forceinline__ void load_aw(const unsigned short* w, int dh, int U0, int wv, int lm,
                                        int kq, bf16x8* aw) {
  const int ga = lm & 3, ula = lm >> 2;
  const int ua = U0 + wv * 4 + ula;
  const unsigned short* wr = w + (size_t)(ga * dh + (ua < dh ? ua : 0)) * (KT * 32);
#pragma unroll
  for (int kt = 0; kt < KT; ++kt) aw[kt] = *(const bf16x8*)&wr[kt * 32 + kq * 8];
}

template <int KT>
__device__ __forceinline__ void mm4(const bf16x8* aw, const unsigned short* lds, int lm, int kq,
                                    f32x4& a0, f32x4& a1, f32x4& a2, f32x4& a3) {
  constexpr int KPP = KT * 32 + 8;
  const unsigned short* rp = lds + lm * KPP + kq * 8;
#pragma unroll
  for (int kt = 0; kt < KT; kt += 4) {
    a0 = __builtin_amdgcn_mfma_f32_16x16x32_bf16(aw[kt], *(const bf16x8*)&rp[kt * 32], a0, 0, 0, 0);
    if (kt + 1 < KT)
      a1 = __builtin_amdgcn_mfma_f32_16x16x32_bf16(aw[kt + 1], *(const bf16x8*)&rp[(kt + 1) * 32],
                                                   a1, 0, 0, 0);
    if (kt + 2 < KT)
      a2 = __builtin_amdgcn_mfma_f32_16x16x32_bf16(aw[kt + 2], *(const bf16x8*)&rp[(kt + 2) * 32],
                                                   a2, 0, 0, 0);
    if (kt + 3 < KT)
      a3 = __builtin_amdgcn_mfma_f32_16x16x32_bf16(aw[kt + 3], *(const bf16x8*)&rp[(kt + 3) * 32],
                                                   a3, 0, 0, 0);
  }
}

__device__ __forceinline__ void pub_h(unsigned short* dst, float hn, bool vu, int kq) {
  unsigned hv = vu ? (unsigned)f2bf(hn) : 0u;
  unsigned t16 = (unsigned)__shfl_xor((int)hv, 16);
  unsigned v32 = (kq & 1) ? (t16 | (hv << 16)) : (hv | (t16 << 16));
  unsigned o32 = (unsigned)__shfl_xor((int)v32, 32);
  if (kq == 0)
    AGENT_ST((unsigned long long*)dst, (unsigned long long)v32 | ((unsigned long long)o32 << 32));
}

__global__ __launch_bounds__(512, 2) void fused_lstm(FP P) {
  __shared__ __align__(16) unsigned short sbuf[16 * 1160 + 16 * 424];
  const int tid = threadIdx.x;
  const int lane = tid & 63;
  const int wv = tid >> 6;
  const int lm = lane & 15;
  const int kq = lane >> 4;
  const int bid = blockIdx.x;
  int* f0 = P.flags;                    // ints [0, 1152)
  int* fh = P.flags + 72 * 16;          // ints [1152, 2304)
  int* f1 = P.flags + 144 * 16;         // ints [2304, 3456)
  int* f2 = P.flags + 216 * 16;         // ints [3456, 3872)
  int* agg = P.flags + 4096;            // ints [4096, 4160) -- DISJOINT (r10 bugfix)

  if (bid >= 242) {  // ---------------- flag aggregators (wave 0 only) ----------------
    if (wv != 0) return;
    const int aset = bid - 242;  // 0: f0/h0, 1: f0/h1, 2: f1/h0, 3: f1/h1
    const int hf = aset & 1;
    const int* fset = (aset < 2) ? f0 : f1;
    int* aline = &agg[aset * 16];
    for (int k = 1; k <= T_ + 1; ++k) {
      for (;;) {
        int v = (lane < 36) ? AGENT_LD(&fset[((lane << 1) + hf) * 16]) : k;
        if (__all(v >= k)) break;
      }
      if (lane == 0) AGENT_ST(aline, k);
    }
    return;
  }

  if (bid < 72) {  // ---------------- L0 recurrence ----------------
    constexpr int KT = 36, KP = 1152;
    const int hf = bid & 1, gid = bid >> 1, U0 = gid * 32;
    const int gb = hf * 16 + lm, un = U0 + wv * 4 + kq;
    const bool vu = un < 1150;
    bf16x8 aw[KT];
    load_aw<KT>(P.whh0, 1150, U0, wv, lm, kq, aw);
    float creg = vu ? P.c0_0[gb * 1150 + un] : 0.f;
    pub_h(P.xc1 + (size_t)gb * KP + U0 + wv * 4, vu ? P.h0_0[gb * 1150 + un] : 0.f, vu, kq);
    asm volatile("s_waitcnt vmcnt(0)" ::: "memory");
    __syncthreads();
    if (tid == 0) AGENT_ST(&f0[(gid * 2 + hf) * 16], 1);
    for (int t = 0; t < T_; ++t) {
      f32x4 cinit = *(const f32x4*)&P.xg[(size_t)(t * 32 + gb) * 4608 + un * 4];
      if (wv == 0) pollone(&agg[hf * 16], t + 1);
      __syncthreads();
      stage<KT>(P.xc1 + (size_t)(t * 32 + hf * 16) * KP, sbuf);
      __syncthreads();
      f32x4 a0 = cinit, a1 = {0.f, 0.f, 0.f, 0.f}, a2 = {0.f, 0.f, 0.f, 0.f},
            a3 = {0.f, 0.f, 0.f, 0.f};
      mm4<KT>(aw, sbuf, lm, kq, a0, a1, a2, a3);
      float gi = a0[0] + a1[0] + a2[0] + a3[0], gf = a0[1] + a1[1] + a2[1] + a3[1];
      float gg = a0[2] + a1[2] + a2[2] + a3[2], go = a0[3] + a1[3] + a2[3] + a3[3];
      float cn = sigf_(gf) * creg + sigf_(gi) * tanhf_(gg);
      float hn = sigf_(go) * tanhf_(cn);
      creg = cn;
      pub_h(P.xc1 + (size_t)((t + 1) * 32 + gb) * KP + U0 + wv * 4, hn, vu, kq);
      if (t == T_ - 1 && vu) { P.oh0[gb * 1150 + un] = hn; P.oc0[gb * 1150 + un] = cn; }
      asm volatile("s_waitcnt vmcnt(0)" ::: "memory");
      __syncthreads();
      if (tid == 0) AGENT_ST(&f0[(gid * 2 + hf) * 16], t + 2);
    }
  } else if (bid < 144) {  // ---------------- L1 input-projection helper ----------------
    constexpr int KT = 36, KP = 1152;
    const int idx = bid - 72, hf = idx & 1, gid = idx >> 1, U0 = gid * 32;
    const int gb = hf * 16 + lm, un = U0 + wv * 4 + kq;
    const bool vu = un < 1150;
    bf16x8 aw[KT];
    load_aw<KT>(P.wih1, 1150, U0, wv, lm, kq, aw);
    f32x4 bini = {0.f, 0.f, 0.f, 0.f};
    if (vu) {
#pragma unroll
      for (int g = 0; g < 4; ++g) bini[g] = P.bih1[g * 1150 + un] + P.bhh1[g * 1150 + un];
    }
    for (int t = 0; t < T_; ++t) {
      if (wv == 0) pollone(&agg[hf * 16], t + 2);  // h0 out of step t = chain0 row t+1
      __syncthreads();
      stage<KT>(P.xc1 + (size_t)((t + 1) * 32 + hf * 16) * KP, sbuf);
      __syncthreads();
      f32x4 a0 = bini, a1 = {0.f, 0.f, 0.f, 0.f}, a2 = {0.f, 0.f, 0.f, 0.f},
            a3 = {0.f, 0.f, 0.f, 0.f};
      mm4<KT>(aw, sbuf, lm, kq, a0, a1, a2, a3);
      float r0 = a0[0] + a1[0] + a2[0] + a3[0], r1 = a0[1] + a1[1] + a2[1] + a3[1];
      float r2 = a0[2] + a1[2] + a2[2] + a3[2], r3 = a0[3] + a1[3] + a2[3] + a3[3];
      // overlay write: xg slot t consumed by L0 at its step t (agg0>=t+2 proves it)
      unsigned long long* dst =
          (unsigned long long*)(P.xg + (size_t)(t * 32 + gb) * 4608 + un * 4);
      AGENT_ST(dst, ((unsigned long long)__float_as_uint(r1) << 32) | __float_as_uint(r0));
      AGENT_ST(dst + 1, ((unsigned long long)__float_as_uint(r3) << 32) | __float_as_uint(r2));
      asm volatile("s_waitcnt vmcnt(0)" ::: "memory");
      __syncthreads();
      if (tid == 0) AGENT_ST(&fh[(gid * 2 + hf) * 16], t + 1);
    }
  } else if (bid < 216) {  // ---------------- L1 recurrence ----------------
    constexpr int KT = 36, KP = 1152;
    const int idx = bid - 144, hf = idx & 1, gid = idx >> 1, U0 = gid * 32;
    const int gb = hf * 16 + lm, un = U0 + wv * 4 + kq;
    const bool vu = un < 1150;
    bf16x8 aw[KT];
    load_aw<KT>(P.whh1, 1150, U0, wv, lm, kq, aw);
    float creg = vu ? P.c0_1[gb * 1150 + un] : 0.f;
    pub_h(P.xc2 + (size_t)gb * KP + U0 + wv * 4, vu ? P.h0_1[gb * 1150 + un] : 0.f, vu, kq);
    asm volatile("s_waitcnt vmcnt(0)" ::: "memory");
    __syncthreads();
    if (tid == 0) AGENT_ST(&f1[(gid * 2 + hf) * 16], 1);
    for (int t = 0; t < T_; ++t) {
      if (wv == 0) pollone(&agg[32 + hf * 16], t + 1);
      else if (wv == 1) pollone(&fh[(gid * 2 + hf) * 16], t + 1);
      __syncthreads();
      stage<KT>(P.xc2 + (size_t)(t * 32 + hf * 16) * KP, sbuf);
      // xg1(t): agent read (overlay lines are stale in L2 from L0's normal reads)
      const unsigned long long* rp =
          (const unsigned long long*)(P.xg + (size_t)(t * 32 + gb) * 4608 + un * 4);
      unsigned long long q0 = AGENT_LD(rp), q1 = AGENT_LD(rp + 1);
      __syncthreads();
      f32x4 a0, a1 = {0.f, 0.f, 0.f, 0.f}, a2 = {0.f, 0.f, 0.f, 0.f}, a3 = {0.f, 0.f, 0.f, 0.f};
      a0[0] = __uint_as_float((unsigned)q0);
      a0[1] = __uint_as_float((unsigned)(q0 >> 32));
      a0[2] = __uint_as_float((unsigned)q1);
      a0[3] = __uint_as_float((unsigned)(q1 >> 32));
      mm4<KT>(aw, sbuf, lm, kq, a0, a1, a2, a3);
      float gi = a0[0] + a1[0] + a2[0] + a3[0], gf = a0[1] + a1[1] + a2[1] + a3[1];
      float gg = a0[2] + a1[2] + a2[2] + a3[2], go = a0[3] + a1[3] + a2[3] + a3[3];
      float cn = sigf_(gf) * creg + sigf_(gi) * tanhf_(gg);
      float hn = sigf_(go) * tanhf_(cn);
      creg = cn;
      pub_h(P.xc2 + (size_t)((t + 1) * 32 + gb) * KP + U0 + wv * 4, hn, vu, kq);
      if (t == T_ - 1 && vu) { P.oh1[gb * 1150 + un] = hn; P.oc1[gb * 1150 + un] = cn; }
      asm volatile("s_waitcnt vmcnt(0)" ::: "memory");
      __syncthreads();
      if (tid == 0) AGENT_ST(&f1[(gid * 2 + hf) * 16], t + 2);
    }
  } else {  // ---------------- L2 combined (input projection + recurrence) ----------------
    constexpr int KTA = 36, KPA = 1152, KTB = 13, KPB = 416;
    const int idx = bid - 216, hf = idx & 1, gid = idx >> 1, U0 = gid * 32;
    const int gb = hf * 16 + lm, un = U0 + wv * 4 + kq;
    const bool vu = un < 400;
    bf16x8 awi[KTA];
    load_aw<KTA>(P.wih2, 400, U0, wv, lm, kq, awi);
    bf16x8 awh[KTB];
    load_aw<KTB>(P.whh2, 400, U0, wv, lm, kq, awh);
    f32x4 bini = {0.f, 0.f, 0.f, 0.f};
    if (vu) {
#pragma unroll
      for (int g = 0; g < 4; ++g) bini[g] = P.bih2[g * 400 + un] + P.bhh2[g * 400 + un];
    }
    float creg = vu ? P.c0_2[gb * 400 + un] : 0.f;
    pub_h(P.xc3 + (size_t)gb * KPB + U0 + wv * 4, vu ? P.h0_2[gb * 400 + un] : 0.f, vu, kq);
    asm volatile("s_waitcnt vmcnt(0)" ::: "memory");
    __syncthreads();
    if (tid == 0) AGENT_ST(&f2[(gid * 2 + hf) * 16], 1);
    unsigned short* h1buf = sbuf;
    unsigned short* h2buf = sbuf + 16 * (KPA + 8);
    for (int t = 0; t < T_; ++t) {
      if (wv == 0) pollone(&agg[32 + hf * 16], t + 2);  // h1 output of step t
      else if (wv == 1) pollset(f2, hf, 13, t + 1);
      __syncthreads();
      stage2<KTA, KTB>(P.xc2 + (size_t)((t + 1) * 32 + hf * 16) * KPA,
                       P.xc3 + (size_t)(t * 32 + hf * 16) * KPB, h1buf, h2buf);
      __syncthreads();
      f32x4 a0 = bini, a1 = {0.f, 0.f, 0.f, 0.f}, a2 = {0.f, 0.f, 0.f, 0.f},
            a3 = {0.f, 0.f, 0.f, 0.f};
      mm4<KTA>(awi, h1buf, lm, kq, a0, a1, a2, a3);
      mm4<KTB>(awh, h2buf, lm, kq, a0, a1, a2, a3);
      float gi = a0[0] + a1[0] + a2[0] + a3[0], gf = a0[1] + a1[1] + a2[1] + a3[1];
      float gg = a0[2] + a1[2] + a2[2] + a3[2], go = a0[3] + a1[3] + a2[3] + a3[3];
      float cn = sigf_(gf) * creg + sigf_(gi) * tanhf_(gg);
      float hn = sigf_(go) * tanhf_(cn);
      creg = cn;
      pub_h(P.xc3 + (size_t)((t + 1) * 32 + gb) * KPB + U0 + wv * 4, hn, vu, kq);
      if (t == T_ - 1 && vu) { P.oh2[gb * 400 + un] = hn; P.oc2[gb * 400 + un] = cn; }
      asm volatile("s_waitcnt vmcnt(0)" ::: "memory");
      __syncthreads();
      if (tid == 0) AGENT_ST(&f2[(gid * 2 + hf) * 16], t + 2);
    }
  }
}

extern "C" void kernel_launch(void* const* d_in, const int* in_sizes, int n_in, void* d_out,
                              int out_size, void* d_ws, size_t ws_size, hipStream_t stream) {
  const int* input = (const int*)d_in[0];
  const float* emb_W = (const float*)d_in[1];
  const float* final_b = (const float*)d_in[2];

  struct L {
    const float *Wih, *Whh, *bih, *bhh, *h0, *c0;
  };
  L ls[3];
  ls[0] = {(const float*)d_in[3],  (const float*)d_in[4],  (const float*)d_in[5],
           (const float*)d_in[6],  (const float*)d_in[7],  (const float*)d_in[8]};
  ls[1] = {(const float*)d_in[9],  (const float*)d_in[10], (const float*)d_in[11],
           (const float*)d_in[12], (const float*)d_in[13], (const float*)d_in[14]};
  ls[2] = {(const float*)d_in[15], (const float*)d_in[16], (const float*)d_in[17],
           (const float*)d_in[18], (const float*)d_in[19], (const float*)d_in[20]};

  // ---- workspace layout ----
  char* base = (char*)d_ws;
  int* flags = (int*)base;                              // 64KB region
  float* xg0 = (float*)(base + 65536);                  // [4096][4608] (overlaid by xg1)
  unsigned short* embbf = (unsigned short*)(xg0 + (size_t)4096 * 4608);
  unsigned short* w0 = embbf + (size_t)33280 * 416;     // Wih0 [4608][416]
  unsigned short* wih1 = w0 + (size_t)4608 * 416;       // [4608][1152]
  unsigned short* whh0 = wih1 + (size_t)4608 * 1152;    // [4600][1152]
  unsigned short* whh1 = whh0 + (size_t)4600 * 1152;    // [4600][1152]
  unsigned short* wih2 = whh1 + (size_t)4600 * 1152;    // [1600][1152]
  unsigned short* whh2 = wih2 + (size_t)1600 * 1152;    // [1600][416]
  unsigned short* xemb = whh2 + (size_t)1600 * 416;     // [4096][416]
  unsigned short* xc1 = xemb + (size_t)4096 * 416;      // [4128][1152]
  unsigned short* xc2 = xc1 + (size_t)4128 * 1152;      // [4128][1152]
  unsigned short* xc3 = xc2 + (size_t)4128 * 1152;      // [4128][416]
  float* out = (float*)d_out;

  hipMemsetAsync(flags, 0, 65536, stream);

  // ---- conversions ----
  {
    long tot = (long)33280 * 416;
    convW<<<(unsigned)((tot + 255) / 256), 256, 0, stream>>>(emb_W, embbf, V_, E_, 416, tot);
  }
  {
    long tot = (long)4608 * 416;
    convW<<<(unsigned)((tot + 255) / 256), 256, 0, stream>>>(ls[0].Wih, w0, 4600, 400, 416, tot);
  }
  {
    long tot = (long)4608 * 1152;
    convW<<<(unsigned)((tot + 255) / 256), 256, 0, stream>>>(ls[1].Wih, wih1, 4600, 1150, 1152,
                                                             tot);
  }
  {
    long tot = (long)4600 * 1152;
    convW<<<(unsigned)((tot + 255) / 256), 256, 0, stream>>>(ls[0].Whh, whh0, 4600, 1150, 1152,
                                                             tot);
    convW<<<(unsigned)((tot + 255) / 256), 256, 0, stream>>>(ls[1].Whh, whh1, 4600, 1150, 1152,
                                                             tot);
  }
  {
    long tot = (long)1600 * 1152;
    convW<<<(unsigned)((tot + 255) / 256), 256, 0, stream>>>(ls[2].Wih, wih2, 1600, 1150, 1152,
                                                             tot);
  }
  {
    long tot = (long)1600 * 416;
    convW<<<(unsigned)((tot + 255) / 256), 256, 0, stream>>>(ls[2].Whh, whh2, 1600, 400, 416, tot);
  }
  embed_kernel<<<(T_ * B_ * 416 + 255) / 256, 256, 0, stream>>>(input, emb_W, xemb);

  long o = (long)T_ * B_ * V_;
  float* oh0 = out + o;
  float* oc0 = oh0 + 32 * 1150;
  float* oh1 = oc0 + 32 * 1150;
  float* oc1 = oh1 + 32 * 1150;
  float* oh2 = oc1 + 32 * 1150;
  float* oc2 = oh2 + 32 * 400;

  // ---- L0 input projection ----
  gemm_bf16<<<dim3(36, 32), 256, 0, stream>>>(xemb, w0, ls[0].bih, ls[0].bhh, xg0, 4096, 416, 4608,
                                              4600, 1150);

  // ---- fused pipelined recurrence (242 workers + 4 aggregators) ----
  FP P;
  P.xg = xg0;
  P.whh0 = whh0;
  P.wih1 = wih1;
  P.whh1 = whh1;
  P.wih2 = wih2;
  P.whh2 = whh2;
  P.h0_0 = ls[0].h0;
  P.c0_0 = ls[0].c0;
  P.h0_1 = ls[1].h0;
  P.c0_1 = ls[1].c0;
  P.h0_2 = ls[2].h0;
  P.c0_2 = ls[2].c0;
  P.bih1 = ls[1].bih;
  P.bhh1 = ls[1].bhh;
  P.bih2 = ls[2].bih;
  P.bhh2 = ls[2].bhh;
  P.xc1 = xc1;
  P.xc2 = xc2;
  P.xc3 = xc3;
  P.oh0 = oh0;
  P.oc0 = oc0;
  P.oh1 = oh1;
  P.oc1 = oc1;
  P.oh2 = oh2;
  P.oc2 = oc2;
  P.flags = flags;
  fused_lstm<<<246, 512, 0, stream>>>(P);

  // ---- tied decoder ----
  gemm_bf16<<<dim3(260, 32), 256, 0, stream>>>(xc3 + (size_t)32 * 416, embbf, final_b, nullptr,
                                               out, 4096, 416, V_, V_, 0);
}